// Round 5
// baseline (226.484 us; speedup 1.0000x reference)
//
#include <hip/hip_runtime.h>
#include <math.h>

// Dims (fixed by the problem)
#define B_SZ 2
#define L_SZ 384
#define D_SZ 384
#define S_SZ 384
#define BLK_ELEMS (L_SZ * D_SZ)        // 147456 per batch
#define TOT_ELEMS (B_SZ * L_SZ * D_SZ) // 294912
#define LOG2E 1.4426950408889634f

__device__ __forceinline__ float fexp2(float x) {
  return __builtin_amdgcn_exp2f(x);
}
__device__ __forceinline__ float softplus_f(float z) {
  return (z > 20.f) ? z : log1pf(__expf(z));
}
// Compiler memory fence: loads issued above cannot sink below, stores below
// cannot hoist above. Used to pin the software pipeline (R4: compiler sank
// prefetch loads to uses -> VGPR_Count 40, 85% stall).
#define PIPELINE_FENCE() asm volatile("" ::: "memory")

// ---------------------------------------------------------------------------
// Dual NT-GEMM: O1 = (softplus?)(A·W1^T + b1), O2 = A·W2^T
// M=768, N=384, K=384. 32(m)x16(n) tile, 128 thr, 2x2 micro.
// grid 24x24 = 576 blocks (2.25/CU -> cross-block overlap of barrier stalls).
// LDS k-major; double-buffered, ONE barrier per chunk:
//   barrier(publish buf) -> compute(buf) -> stage(buf^1) -> gload(cc+2)
// stage's source regs were loaded one full compute-phase earlier.
// ---------------------------------------------------------------------------
template <bool SP>
__global__ __launch_bounds__(128, 4) void dual_gemm_nt(
    const float* __restrict__ A, const float* __restrict__ W1,
    const float* __restrict__ W2, const float* __restrict__ b1,
    float* __restrict__ O1, float* __restrict__ O2) {
  __shared__ float As[2][32][33];        // [buf][k][m]
  __shared__ float Ws[2][2][32][17];     // [buf][which][k][n]

  const int t = threadIdx.x;
  const int tx = t & 7;    // n micro (2 cols)
  const int ty = t >> 3;   // m micro (2 rows), 0..15
  const int m0 = blockIdx.y * 32;
  const int n0 = blockIdx.x * 16;
  // staging indices
  const int am = t >> 2;          // 0..31
  const int ak = (t & 3) * 8;     // 0,8,16,24
  const int wn = t >> 3;          // 0..15
  const int wk = (t & 7) * 4;     // 0..28

  float4 a0r, a1r, w1r, w2r;
  auto gload = [&](int kt) {
    a0r = *(const float4*)(A + (m0 + am) * 384 + kt + ak);
    a1r = *(const float4*)(A + (m0 + am) * 384 + kt + ak + 4);
    w1r = *(const float4*)(W1 + (n0 + wn) * 384 + kt + wk);
    w2r = *(const float4*)(W2 + (n0 + wn) * 384 + kt + wk);
  };
  auto stage = [&](int buf) {
    const float* a0p = &a0r.x;
    const float* a1p = &a1r.x;
    const float* w1p = &w1r.x;
    const float* w2p = &w2r.x;
#pragma unroll
    for (int q = 0; q < 4; ++q) {
      As[buf][ak + q][am] = a0p[q];
      As[buf][ak + 4 + q][am] = a1p[q];
      Ws[buf][0][wk + q][wn] = w1p[q];
      Ws[buf][1][wk + q][wn] = w2p[q];
    }
  };

  float acc1[2][2] = {{0.f, 0.f}, {0.f, 0.f}};
  float acc2[2][2] = {{0.f, 0.f}, {0.f, 0.f}};

  gload(0);
  stage(0);
  gload(32);

  for (int cc = 0; cc < 12; ++cc) {
    const int buf = cc & 1;
    __syncthreads();  // publish buf (staged at end of previous iteration)
#pragma unroll
    for (int k = 0; k < 32; ++k) {
      const float2 av = *(const float2*)&As[buf][k][2 * ty];
      const float2 w1 = *(const float2*)&Ws[buf][0][k][2 * tx];
      const float2 w2 = *(const float2*)&Ws[buf][1][k][2 * tx];
      acc1[0][0] = fmaf(av.x, w1.x, acc1[0][0]);
      acc1[0][1] = fmaf(av.x, w1.y, acc1[0][1]);
      acc1[1][0] = fmaf(av.y, w1.x, acc1[1][0]);
      acc1[1][1] = fmaf(av.y, w1.y, acc1[1][1]);
      acc2[0][0] = fmaf(av.x, w2.x, acc2[0][0]);
      acc2[0][1] = fmaf(av.x, w2.y, acc2[0][1]);
      acc2[1][0] = fmaf(av.y, w2.x, acc2[1][0]);
      acc2[1][1] = fmaf(av.y, w2.y, acc2[1][1]);
    }
    if (cc + 1 < 12) {
      stage(buf ^ 1);                       // regs from gload(cc+1)
      if (cc + 2 < 12) gload((cc + 2) * 32);  // in flight across next compute
    }
  }

  const int q0 = n0 + 2 * tx;
#pragma unroll
  for (int r = 0; r < 2; ++r) {
    const int row = m0 + 2 * ty + r;
    float2 o1, o2;
    if constexpr (SP) {
      o1.x = softplus_f(acc1[r][0] + b1[q0]);
      o1.y = softplus_f(acc1[r][1] + b1[q0 + 1]);
    } else {
      o1.x = acc1[r][0];
      o1.y = acc1[r][1];
    }
    o2.x = acc2[r][0];
    o2.y = acc2[r][1];
    *(float2*)(O1 + row * 384 + q0) = o1;
    *(float2*)(O2 + row * 384 + q0) = o2;
  }
}

// ---------------------------------------------------------------------------
// Causal depthwise conv (k=4, left pad 3) + bias + SiLU -> u; also dtu = dt*u
// ---------------------------------------------------------------------------
__global__ __launch_bounds__(256) void conv_silu_kernel(
    const float* __restrict__ x, const float* __restrict__ cw,
    const float* __restrict__ cb, const float* __restrict__ dt,
    float* __restrict__ u, float* __restrict__ dtu) {
  const int idx = blockIdx.x * 256 + threadIdx.x;
  const int i = idx % D_SZ;
  const int l = (idx / D_SZ) % L_SZ;
  const int b = idx / BLK_ELEMS;
  float acc = cb[i];
#pragma unroll
  for (int t = 0; t < 4; t++) {
    const int ls = l - 3 + t;
    const float xv = (ls >= 0) ? x[(b * L_SZ + ls) * D_SZ + i] : 0.f;
    acc = fmaf(xv, cw[i * 4 + t], acc);
  }
  const float uv = acc / (1.f + __expf(-acc));
  u[idx] = uv;
  dtu[idx] = dt[idx] * uv;
}

// ---------------------------------------------------------------------------
// Selective scan v5: 3-way j-split (wave w owns states j = 128w+2*lane+e),
// 2304 independent waves, no barriers. Triple-buffered register pipeline
// pinned by PIPELINE_FENCE (loads for chunk c+2 in flight across two full
// chunk computes ~1000 cyc). Reduction: value-folding butterfly (8 partials
// folded into lanes, 3 select+shfl stages + 3 shfl-adds); lanes 0..7 store
// 8 consecutive l to [w][b][i][l]-major partials (contiguous 32B).
// u*D is applied by the combine kernel.
// ---------------------------------------------------------------------------
#define CH 8
__global__ __launch_bounds__(64, 3) void scan_kernel(
    const float* __restrict__ A_log, const float* __restrict__ dt,
    const float* __restrict__ dtu, const float* __restrict__ Bm,
    const float* __restrict__ Cm, float* __restrict__ p0,
    float* __restrict__ p1, float* __restrict__ p2) {
  const int bid = blockIdx.x;  // 0..2303
  const int sid = bid / 3;
  const int w = bid % 3;
  const int b = sid / D_SZ;
  const int i = sid % D_SZ;
  const int lane = threadIdx.x;
  const int j0 = w * 128 + 2 * lane;

  const float2 av = *(const float2*)(A_log + i * S_SZ + j0);
  const float2 bv = *(const float2*)(Bm + (b * D_SZ + i) * S_SZ + j0);
  const float a20 = -__expf(av.x) * LOG2E;
  const float a21 = -__expf(av.y) * LOG2E;
  const float bw0 = bv.x, bw1 = bv.y;
  float h0 = 0.f, h1 = 0.f;

  const float* dtp = dt + b * BLK_ELEMS + i;
  const float* dup = dtu + b * BLK_ELEMS + i;
  const float* cp = Cm + b * BLK_ELEMS + j0;
  float* psel = (w == 0) ? p0 : ((w == 1) ? p1 : p2);
  float* pp = psel + (b * D_SZ + i) * L_SZ;  // [i][l]-major partial row

  // fold target: lane r (r<8) ends owning step s = bitrev3(r)
  const int sidx = ((lane & 1) << 2) | (lane & 2) | ((lane >> 2) & 1);
  const bool storer = lane < 8;

  float C0[16], D0[8], U0[8];
  float C1[16], D1[8], U1[8];
  float C2[16], D2[8], U2[8];

  auto load_chunk = [&](int c, float (&cx)[16], float (&dx)[8],
                        float (&ux)[8]) {
    const int l0 = c * CH;
#pragma unroll
    for (int s = 0; s < CH; ++s) {
      const int l = (l0 + s < L_SZ) ? (l0 + s) : (L_SZ - 1);
      dx[s] = dtp[l * D_SZ];
      ux[s] = dup[l * D_SZ];
      const float2 c2 = *(const float2*)(cp + l * D_SZ);
      cx[2 * s] = c2.x;
      cx[2 * s + 1] = c2.y;
    }
  };

  auto compute_chunk = [&](int c, const float (&cx)[16], const float (&dx)[8],
                           const float (&ux)[8]) {
    float accs[8];
#pragma unroll
    for (int s = 0; s < CH; ++s) {
      const float dts = dx[s];
      const float dtus = ux[s];
      const float e0 = fexp2(dts * a20);
      const float e1 = fexp2(dts * a21);
      h0 = fmaf(e0, h0, bw0 * dtus);
      h1 = fmaf(e1, h1, bw1 * dtus);
      accs[s] = fmaf(h1, cx[2 * s + 1], h0 * cx[2 * s]);
    }
    // fold 8 values into lanes: stage d, halving the live array
    {
      const bool s1 = (lane & 1) != 0;
#pragma unroll
      for (int q = 0; q < 4; ++q) {
        const float keep = s1 ? accs[q + 4] : accs[q];
        const float send = s1 ? accs[q] : accs[q + 4];
        accs[q] = keep + __shfl_xor(send, 1, 64);
      }
      const bool s2 = (lane & 2) != 0;
#pragma unroll
      for (int q = 0; q < 2; ++q) {
        const float keep = s2 ? accs[q + 2] : accs[q];
        const float send = s2 ? accs[q] : accs[q + 2];
        accs[q] = keep + __shfl_xor(send, 2, 64);
      }
      const bool s3 = (lane & 4) != 0;
      {
        const float keep = s3 ? accs[1] : accs[0];
        const float send = s3 ? accs[0] : accs[1];
        accs[0] = keep + __shfl_xor(send, 4, 64);
      }
    }
    float r = accs[0];
    r += __shfl_xor(r, 8, 64);
    r += __shfl_xor(r, 16, 64);
    r += __shfl_xor(r, 32, 64);
    if (storer) pp[c * CH + sidx] = r;
  };

  load_chunk(0, C0, D0, U0);
  load_chunk(1, C1, D1, U1);
  for (int it = 0; it < 16; ++it) {
    const int c = 3 * it;
    load_chunk((c + 2 < 48) ? c + 2 : 47, C2, D2, U2);
    PIPELINE_FENCE();
    compute_chunk(c, C0, D0, U0);
    load_chunk((c + 3 < 48) ? c + 3 : 47, C0, D0, U0);
    PIPELINE_FENCE();
    compute_chunk(c + 1, C1, D1, U1);
    load_chunk((c + 4 < 48) ? c + 4 : 47, C1, D1, U1);
    PIPELINE_FENCE();
    compute_chunk(c + 2, C2, D2, U2);
  }
}

// ---------------------------------------------------------------------------
// Combine + transpose: y[b,l,i] = p0+p1+p2 (stored [b,i,l]) + u[b,l,i]*D[i]
// 32x32 LDS transpose tiles; all global accesses coalesced.
// ---------------------------------------------------------------------------
__global__ __launch_bounds__(256) void combine_kernel(
    const float* __restrict__ p0, const float* __restrict__ p1,
    const float* __restrict__ p2, const float* __restrict__ u,
    const float* __restrict__ Dv, float* __restrict__ y) {
  __shared__ float T[32][33];
  const int tx = threadIdx.x;        // 0..31
  const int ty0 = threadIdx.y;       // 0..7
  const int b = blockIdx.z;
  const int i0 = blockIdx.y * 32;
  const int l0 = blockIdx.x * 32;
#pragma unroll
  for (int r = 0; r < 4; ++r) {
    const int il = ty0 + 8 * r;                       // i_local
    const int off = (b * D_SZ + i0 + il) * L_SZ + l0 + tx;
    T[il][tx] = p0[off] + p1[off] + p2[off];
  }
  __syncthreads();
#pragma unroll
  for (int r = 0; r < 4; ++r) {
    const int ll = ty0 + 8 * r;                       // l_local
    const int gi = i0 + tx;
    const int off = (b * L_SZ + l0 + ll) * D_SZ + gi;
    y[off] = fmaf(u[off], Dv[gi], T[tx][ll]);
  }
}

extern "C" void kernel_launch(void* const* d_in, const int* in_sizes, int n_in,
                              void* d_out, int out_size, void* d_ws,
                              size_t ws_size, hipStream_t stream) {
  const float* x = (const float*)d_in[0];
  const float* A_log = (const float*)d_in[1];
  const float* D = (const float*)d_in[2];
  const float* dt_w = (const float*)d_in[3];
  const float* dt_b = (const float*)d_in[4];
  const float* B_w = (const float*)d_in[5];
  const float* C_w = (const float*)d_in[6];
  const float* conv_w = (const float*)d_in[7];
  const float* conv_b = (const float*)d_in[8];
  float* y = (float*)d_out;

  float* ws = (float*)d_ws;
  float* dt = ws;                    // slot 0
  float* xdbl = ws + TOT_ELEMS;      // slot 1 (reused as p0 after GEMM2)
  float* Bm = ws + 2 * TOT_ELEMS;    // slot 2
  float* Cm = ws + 3 * TOT_ELEMS;    // slot 3
  float* u = ws + 4 * TOT_ELEMS;     // slot 4
  float* dtu = ws + 5 * TOT_ELEMS;   // slot 5
  float* p1 = ws + 6 * TOT_ELEMS;    // slot 6
  float* p2 = ws + 7 * TOT_ELEMS;    // slot 7 (total 9.4 MB)
  float* p0 = xdbl;                  // xdbl dead after GEMM2

  const dim3 gemm_grid(S_SZ / 16, (B_SZ * L_SZ) / 32);  // 24 x 24 = 576
  dual_gemm_nt<true><<<gemm_grid, 128, 0, stream>>>(x, dt_w, B_w, dt_b, dt, xdbl);
  dual_gemm_nt<false><<<gemm_grid, 128, 0, stream>>>(xdbl, B_w, C_w, nullptr, Bm, Cm);
  conv_silu_kernel<<<TOT_ELEMS / 256, 256, 0, stream>>>(x, conv_w, conv_b, dt, u, dtu);
  scan_kernel<<<3 * B_SZ * D_SZ, 64, 0, stream>>>(A_log, dt, dtu, Bm, Cm, p0, p1, p2);
  combine_kernel<<<dim3(L_SZ / 32, D_SZ / 32, B_SZ), dim3(32, 8), 0, stream>>>(
      p0, p1, p2, u, D, y);
}

// Round 6
// 155.575 us; speedup vs baseline: 1.4558x; 1.4558x over previous
//
#include <hip/hip_runtime.h>
#include <math.h>

// Dims (fixed by the problem)
#define B_SZ 2
#define L_SZ 384
#define D_SZ 384
#define S_SZ 384
#define BLK_ELEMS (L_SZ * D_SZ)        // 147456 per batch
#define TOT_ELEMS (B_SZ * L_SZ * D_SZ) // 294912
#define LOG2E 1.4426950408889634f

typedef __attribute__((ext_vector_type(8))) short bf16x8;
typedef __attribute__((ext_vector_type(4))) float f32x4;

__device__ __forceinline__ float fexp2(float x) {
  return __builtin_amdgcn_exp2f(x);
}
__device__ __forceinline__ float softplus_f(float z) {
  return (z > 20.f) ? z : log1pf(__expf(z));
}
__device__ __forceinline__ unsigned short f2bf(float f) {  // RNE f32->bf16
  unsigned int u = __float_as_uint(f);
  return (unsigned short)((u + 0x7FFFu + ((u >> 16) & 1u)) >> 16);
}
// Compiler scheduling fence (R4/R5: stops prefetch-load sinking).
#define PIPELINE_FENCE() asm volatile("" ::: "memory")

// ---------------------------------------------------------------------------
// Convert x, dt_w, B_w, C_w to bf16. Block-segmented so no per-thread branch.
// ---------------------------------------------------------------------------
__global__ __launch_bounds__(256) void cvt_bf16_kernel(
    const float* __restrict__ x, const float* __restrict__ dt_w,
    const float* __restrict__ B_w, const float* __restrict__ C_w,
    unsigned short* __restrict__ xbf, unsigned short* __restrict__ dtwbf,
    unsigned short* __restrict__ Bwbf, unsigned short* __restrict__ Cwbf) {
  const int blk = blockIdx.x;
  const float* src;
  unsigned short* dst;
  int base;
  if (blk < 288) { src = x; dst = xbf; base = blk; }
  else if (blk < 432) { src = dt_w; dst = dtwbf; base = blk - 288; }
  else if (blk < 576) { src = B_w; dst = Bwbf; base = blk - 432; }
  else { src = C_w; dst = Cwbf; base = blk - 576; }
  const int idx = base * 1024 + threadIdx.x * 4;
  const float4 v = *(const float4*)(src + idx);
  ushort4 o;
  o.x = f2bf(v.x); o.y = f2bf(v.y); o.z = f2bf(v.z); o.w = f2bf(v.w);
  *(ushort4*)(dst + idx) = o;
}

// ---------------------------------------------------------------------------
// Barrier-free dual MFMA NT-GEMM. One wave per 16x16 output tile,
// K=384 = 12 x mfma_f32_16x16x32_bf16 per output (O1 and O2 share A).
// All 36 16-B fragment loads are independent and issued before any MFMA:
// one latency burst, no LDS, no __syncthreads (R5 post-mortem: chunked
// LDS pipelines = 12 serialized latency waves at 95% stall).
// Layouts (m89/m91-verified): A/B frag = [lane&15][quad*8+j] (row-major NT
// rows, 16B contiguous); C/D: col=lane&15, row=quad*4+reg.
// MODE 1: O1 = softplus(acc1+bias) f32, O2 = bf16(acc2)  [dt, x_dbl]
// MODE 2: O1 = acc1 f32, O2 = acc2 f32                   [Bm, Cm]
// ---------------------------------------------------------------------------
template <int MODE>
__global__ __launch_bounds__(256) void mfma_dual_gemm(
    const unsigned short* __restrict__ Abf,
    const unsigned short* __restrict__ W1bf,
    const unsigned short* __restrict__ W2bf,
    const float* __restrict__ bias,
    float* __restrict__ O1, void* __restrict__ O2v) {
  const int wid = ((blockIdx.x << 8) + (int)threadIdx.x) >> 6;  // 0..1151
  const int mt = wid / 24;        // 0..47
  const int nt = wid - mt * 24;   // 0..23
  const int lane = threadIdx.x & 63;
  const int rc = lane & 15;
  const int quad = lane >> 4;

  const unsigned short* ap = Abf + (mt * 16 + rc) * 384 + quad * 8;
  const unsigned short* w1p = W1bf + (nt * 16 + rc) * 384 + quad * 8;
  const unsigned short* w2p = W2bf + (nt * 16 + rc) * 384 + quad * 8;

  bf16x8 af[12], w1f[12], w2f[12];
#pragma unroll
  for (int kt = 0; kt < 12; ++kt) {
    af[kt] = *(const bf16x8*)(ap + kt * 32);
    w1f[kt] = *(const bf16x8*)(w1p + kt * 32);
    w2f[kt] = *(const bf16x8*)(w2p + kt * 32);
  }
  PIPELINE_FENCE();
  f32x4 acc1 = {0.f, 0.f, 0.f, 0.f};
  f32x4 acc2 = {0.f, 0.f, 0.f, 0.f};
#pragma unroll
  for (int kt = 0; kt < 12; ++kt) {
    acc1 = __builtin_amdgcn_mfma_f32_16x16x32_bf16(af[kt], w1f[kt], acc1, 0, 0, 0);
    acc2 = __builtin_amdgcn_mfma_f32_16x16x32_bf16(af[kt], w2f[kt], acc2, 0, 0, 0);
  }
  const int col = nt * 16 + rc;
  const int row0 = mt * 16 + quad * 4;
  if constexpr (MODE == 1) {
    unsigned short* O2 = (unsigned short*)O2v;
    const float bb = bias[col];
#pragma unroll
    for (int r = 0; r < 4; ++r) {
      O1[(row0 + r) * 384 + col] = softplus_f(acc1[r] + bb);
      O2[(row0 + r) * 384 + col] = f2bf(acc2[r]);
    }
  } else {
    float* O2 = (float*)O2v;
#pragma unroll
    for (int r = 0; r < 4; ++r) {
      O1[(row0 + r) * 384 + col] = acc1[r];
      O2[(row0 + r) * 384 + col] = acc2[r];
    }
  }
}

// ---------------------------------------------------------------------------
// Causal depthwise conv (k=4, left pad 3) + bias + SiLU -> u; also dtu = dt*u
// ---------------------------------------------------------------------------
__global__ __launch_bounds__(256) void conv_silu_kernel(
    const float* __restrict__ x, const float* __restrict__ cw,
    const float* __restrict__ cb, const float* __restrict__ dt,
    float* __restrict__ u, float* __restrict__ dtu) {
  const int idx = blockIdx.x * 256 + threadIdx.x;
  const int i = idx % D_SZ;
  const int l = (idx / D_SZ) % L_SZ;
  const int b = idx / BLK_ELEMS;
  float acc = cb[i];
#pragma unroll
  for (int t = 0; t < 4; t++) {
    const int ls = l - 3 + t;
    const float xv = (ls >= 0) ? x[(b * L_SZ + ls) * D_SZ + i] : 0.f;
    acc = fmaf(xv, cw[i * 4 + t], acc);
  }
  const float uv = acc / (1.f + __expf(-acc));
  u[idx] = uv;
  dtu[idx] = dt[idx] * uv;
}

// ---------------------------------------------------------------------------
// Selective scan v5 (kept from R5): 3-way j-split, 2304 independent waves,
// triple-buffered register pipeline pinned by fences, value-folding
// butterfly reduction; partials stored [b][i][l]-major; u*D in combine.
// ---------------------------------------------------------------------------
#define CH 8
__global__ __launch_bounds__(64, 3) void scan_kernel(
    const float* __restrict__ A_log, const float* __restrict__ dt,
    const float* __restrict__ dtu, const float* __restrict__ Bm,
    const float* __restrict__ Cm, float* __restrict__ p0,
    float* __restrict__ p1, float* __restrict__ p2) {
  const int bid = blockIdx.x;  // 0..2303
  const int sid = bid / 3;
  const int w = bid % 3;
  const int b = sid / D_SZ;
  const int i = sid % D_SZ;
  const int lane = threadIdx.x;
  const int j0 = w * 128 + 2 * lane;

  const float2 av = *(const float2*)(A_log + i * S_SZ + j0);
  const float2 bv = *(const float2*)(Bm + (b * D_SZ + i) * S_SZ + j0);
  const float a20 = -__expf(av.x) * LOG2E;
  const float a21 = -__expf(av.y) * LOG2E;
  const float bw0 = bv.x, bw1 = bv.y;
  float h0 = 0.f, h1 = 0.f;

  const float* dtp = dt + b * BLK_ELEMS + i;
  const float* dup = dtu + b * BLK_ELEMS + i;
  const float* cp = Cm + b * BLK_ELEMS + j0;
  float* psel = (w == 0) ? p0 : ((w == 1) ? p1 : p2);
  float* pp = psel + (b * D_SZ + i) * L_SZ;  // [i][l]-major partial row

  const int sidx = ((lane & 1) << 2) | (lane & 2) | ((lane >> 2) & 1);
  const bool storer = lane < 8;

  float C0[16], D0[8], U0[8];
  float C1[16], D1[8], U1[8];
  float C2[16], D2[8], U2[8];

  auto load_chunk = [&](int c, float (&cx)[16], float (&dx)[8],
                        float (&ux)[8]) {
    const int l0 = c * CH;
#pragma unroll
    for (int s = 0; s < CH; ++s) {
      const int l = (l0 + s < L_SZ) ? (l0 + s) : (L_SZ - 1);
      dx[s] = dtp[l * D_SZ];
      ux[s] = dup[l * D_SZ];
      const float2 c2 = *(const float2*)(cp + l * D_SZ);
      cx[2 * s] = c2.x;
      cx[2 * s + 1] = c2.y;
    }
  };

  auto compute_chunk = [&](int c, const float (&cx)[16], const float (&dx)[8],
                           const float (&ux)[8]) {
    float accs[8];
#pragma unroll
    for (int s = 0; s < CH; ++s) {
      const float dts = dx[s];
      const float dtus = ux[s];
      const float e0 = fexp2(dts * a20);
      const float e1 = fexp2(dts * a21);
      h0 = fmaf(e0, h0, bw0 * dtus);
      h1 = fmaf(e1, h1, bw1 * dtus);
      accs[s] = fmaf(h1, cx[2 * s + 1], h0 * cx[2 * s]);
    }
    {
      const bool s1 = (lane & 1) != 0;
#pragma unroll
      for (int q = 0; q < 4; ++q) {
        const float keep = s1 ? accs[q + 4] : accs[q];
        const float send = s1 ? accs[q] : accs[q + 4];
        accs[q] = keep + __shfl_xor(send, 1, 64);
      }
      const bool s2 = (lane & 2) != 0;
#pragma unroll
      for (int q = 0; q < 2; ++q) {
        const float keep = s2 ? accs[q + 2] : accs[q];
        const float send = s2 ? accs[q] : accs[q + 2];
        accs[q] = keep + __shfl_xor(send, 2, 64);
      }
      const bool s3 = (lane & 4) != 0;
      {
        const float keep = s3 ? accs[1] : accs[0];
        const float send = s3 ? accs[0] : accs[1];
        accs[0] = keep + __shfl_xor(send, 4, 64);
      }
    }
    float r = accs[0];
    r += __shfl_xor(r, 8, 64);
    r += __shfl_xor(r, 16, 64);
    r += __shfl_xor(r, 32, 64);
    if (storer) pp[c * CH + sidx] = r;
  };

  load_chunk(0, C0, D0, U0);
  load_chunk(1, C1, D1, U1);
  for (int it = 0; it < 16; ++it) {
    const int c = 3 * it;
    load_chunk((c + 2 < 48) ? c + 2 : 47, C2, D2, U2);
    PIPELINE_FENCE();
    compute_chunk(c, C0, D0, U0);
    load_chunk((c + 3 < 48) ? c + 3 : 47, C0, D0, U0);
    PIPELINE_FENCE();
    compute_chunk(c + 1, C1, D1, U1);
    load_chunk((c + 4 < 48) ? c + 4 : 47, C1, D1, U1);
    PIPELINE_FENCE();
    compute_chunk(c + 2, C2, D2, U2);
  }
}

// ---------------------------------------------------------------------------
// Combine + transpose: y[b,l,i] = p0+p1+p2 (stored [b,i,l]) + u[b,l,i]*D[i]
// ---------------------------------------------------------------------------
__global__ __launch_bounds__(256) void combine_kernel(
    const float* __restrict__ p0, const float* __restrict__ p1,
    const float* __restrict__ p2, const float* __restrict__ u,
    const float* __restrict__ Dv, float* __restrict__ y) {
  __shared__ float T[32][33];
  const int tx = threadIdx.x;        // 0..31
  const int ty0 = threadIdx.y;       // 0..7
  const int b = blockIdx.z;
  const int i0 = blockIdx.y * 32;
  const int l0 = blockIdx.x * 32;
#pragma unroll
  for (int r = 0; r < 4; ++r) {
    const int il = ty0 + 8 * r;
    const int off = (b * D_SZ + i0 + il) * L_SZ + l0 + tx;
    T[il][tx] = p0[off] + p1[off] + p2[off];
  }
  __syncthreads();
#pragma unroll
  for (int r = 0; r < 4; ++r) {
    const int ll = ty0 + 8 * r;
    const int gi = i0 + tx;
    const int off = (b * L_SZ + l0 + ll) * D_SZ + gi;
    y[off] = fmaf(u[off], Dv[gi], T[tx][ll]);
  }
}

extern "C" void kernel_launch(void* const* d_in, const int* in_sizes, int n_in,
                              void* d_out, int out_size, void* d_ws,
                              size_t ws_size, hipStream_t stream) {
  const float* x = (const float*)d_in[0];
  const float* A_log = (const float*)d_in[1];
  const float* D = (const float*)d_in[2];
  const float* dt_w = (const float*)d_in[3];
  const float* dt_b = (const float*)d_in[4];
  const float* B_w = (const float*)d_in[5];
  const float* C_w = (const float*)d_in[6];
  const float* conv_w = (const float*)d_in[7];
  const float* conv_b = (const float*)d_in[8];
  float* y = (float*)d_out;

  float* ws = (float*)d_ws;
  float* dt = ws;                    // slot 0
  float* p0 = ws + TOT_ELEMS;        // slot 1
  float* Bm = ws + 2 * TOT_ELEMS;    // slot 2
  float* Cm = ws + 3 * TOT_ELEMS;    // slot 3
  float* u = ws + 4 * TOT_ELEMS;     // slot 4
  float* dtu = ws + 5 * TOT_ELEMS;   // slot 5
  float* p1 = ws + 6 * TOT_ELEMS;    // slot 6
  float* p2 = ws + 7 * TOT_ELEMS;    // slot 7
  // bf16 area (ushort), after the 8 f32 slots (~9.4 MB + ~2.1 MB)
  unsigned short* bfarea = (unsigned short*)(ws + 8 * TOT_ELEMS);
  unsigned short* xbf = bfarea;                    // 294912
  unsigned short* dtwbf = bfarea + 294912;         // 147456
  unsigned short* Bwbf = bfarea + 442368;          // 147456
  unsigned short* Cwbf = bfarea + 589824;          // 147456
  unsigned short* xdblbf = bfarea + 737280;        // 294912

  cvt_bf16_kernel<<<720, 256, 0, stream>>>(x, dt_w, B_w, C_w, xbf, dtwbf, Bwbf, Cwbf);
  // GEMM1: dt = softplus(x·dt_w^T + b), x_dbl(bf16) = x·B_w^T
  mfma_dual_gemm<1><<<288, 256, 0, stream>>>(xbf, dtwbf, Bwbf, dt_b, dt, xdblbf);
  // GEMM2: Bm = x_dbl·B_w^T, Cm = x_dbl·C_w^T
  mfma_dual_gemm<2><<<288, 256, 0, stream>>>(xdblbf, Bwbf, Cwbf, nullptr, Bm, Cm);
  conv_silu_kernel<<<TOT_ELEMS / 256, 256, 0, stream>>>(x, conv_w, conv_b, dt, u, dtu);
  scan_kernel<<<3 * B_SZ * D_SZ, 64, 0, stream>>>(A_log, dt, dtu, Bm, Cm, p0, p1, p2);
  combine_kernel<<<dim3(L_SZ / 32, D_SZ / 32, B_SZ), dim3(32, 8), 0, stream>>>(
      p0, p1, p2, u, D, y);
}